// Round 3
// baseline (969.552 us; speedup 1.0000x reference)
//
#include <hip/hip_runtime.h>

typedef __bf16 bf16_t;
typedef bf16_t bf16x8 __attribute__((ext_vector_type(8)));
typedef bf16_t bf16x4 __attribute__((ext_vector_type(4)));
typedef float f32x4 __attribute__((ext_vector_type(4)));

#define N_PTS 8192
#define C_DIM 256
#define K_NN 16

// ---------------------------------------------------------------- prep: cast feats to bf16
__global__ __launch_bounds__(256) void cast_feats_kernel(const float* __restrict__ f,
                                                         bf16_t* __restrict__ fb) {
    int i = (blockIdx.x * 256 + threadIdx.x) * 4;
    float4 v = *(const float4*)(f + i);
    bf16x4 o;
    o[0] = (bf16_t)v.x; o[1] = (bf16_t)v.y; o[2] = (bf16_t)v.z; o[3] = (bf16_t)v.w;
    *(bf16x4*)(fb + i) = o;
}

// ---------------------------------------------------------------- prep: transpose+cast 5 weight mats to Wt[n][k] bf16
__global__ __launch_bounds__(256) void prep_weights_kernel(
    const float* __restrict__ w0, const float* __restrict__ w1,
    const float* __restrict__ w2, const float* __restrict__ w3,
    const float* __restrict__ w4, bf16_t* __restrict__ wt_base) {
    __shared__ float tile[64][65];
    int m = blockIdx.z;
    const float* src = (m == 0) ? w0 : (m == 1) ? w1 : (m == 2) ? w2 : (m == 3) ? w3 : w4;
    bf16_t* dst = wt_base + m * (C_DIM * C_DIM);
    int k0 = blockIdx.x * 64, n0 = blockIdx.y * 64;
    int tr = threadIdx.x >> 6, tc = threadIdx.x & 63;
#pragma unroll
    for (int i = 0; i < 16; ++i) {
        int r = i * 4 + tr;
        tile[r][tc] = src[(k0 + r) * C_DIM + (n0 + tc)];
    }
    __syncthreads();
#pragma unroll
    for (int i = 0; i < 16; ++i) {
        int r = i * 4 + tr;
        dst[(n0 + r) * C_DIM + (k0 + tc)] = (bf16_t)tile[tc][r];
    }
}

// ---------------------------------------------------------------- KNN: one wave per query point
// Emulate the numpy reference's fp32 rounding EXACTLY (don't be more accurate than the ref):
//   sq_i   = (fl(x^2)+fl(y^2))+fl(z^2)        (no fma, left-to-right — np.sum of products)
//   dot    = fma(z,z', fma(y,y', fl(x*x')))   (BLAS sgemm/syrk sequential-k fma microkernel)
//   d2     = fl(fl(sq_i+sq_j) - fl(2*dot))
// The ref's d2 carries +-0.002 rounding vs exact; at ~1 point/8k that flips the 16th
// neighbor. Matching its bit pattern selects the same set; downstream is k-permutation-
// invariant so order doesn't matter. Ties -> lower index (stable top_k).
__global__ __launch_bounds__(64) void knn_kernel(const float* __restrict__ coords,
                                                 int* __restrict__ idx_out) {
    const int n = blockIdx.x;
    const int lane = threadIdx.x;
    const float qx = coords[3 * n + 0], qy = coords[3 * n + 1], qz = coords[3 * n + 2];
    const float sqi = __fadd_rn(__fadd_rn(__fmul_rn(qx, qx), __fmul_rn(qy, qy)),
                                __fmul_rn(qz, qz));

    float bd[16];
    int bi[16];
#pragma unroll
    for (int i = 0; i < 16; ++i) { bd[i] = 3.4e38f; bi[i] = 0x7fffffff; }

    for (int j = lane; j < N_PTS; j += 64) {
        float xj = coords[3 * j + 0], yj = coords[3 * j + 1], zj = coords[3 * j + 2];
        float sqj = __fadd_rn(__fadd_rn(__fmul_rn(xj, xj), __fmul_rn(yj, yj)),
                              __fmul_rn(zj, zj));
        float dot = __fmaf_rn(zj, qz, __fmaf_rn(yj, qy, __fmul_rn(xj, qx)));
        float d2 = __fsub_rn(__fadd_rn(sqi, sqj), __fmul_rn(2.0f, dot));
        bool acc = (d2 < bd[15]) || (d2 == bd[15] && j < bi[15]);
        if (acc) {
            bd[15] = d2; bi[15] = j;
#pragma unroll
            for (int s = 15; s > 0; --s) {
                bool sw = (bd[s] < bd[s - 1]) || (bd[s] == bd[s - 1] && bi[s] < bi[s - 1]);
                if (sw) {
                    float td = bd[s]; bd[s] = bd[s - 1]; bd[s - 1] = td;
                    int ti = bi[s]; bi[s] = bi[s - 1]; bi[s - 1] = ti;
                }
            }
        }
    }

    // merge 64 sorted lists: 16 rounds of wave-argmin on packed (ordered_dist, idx) keys
    int keep = 0;
#pragma unroll 1
    for (int it = 0; it < 16; ++it) {
        unsigned u = __float_as_uint(bd[0]);
        u = (u & 0x80000000u) ? ~u : (u | 0x80000000u);
        unsigned long long key = (((unsigned long long)u) << 32) | (unsigned)bi[0];
        unsigned long long k = key;
#pragma unroll
        for (int off = 1; off < 64; off <<= 1) {
            unsigned long long o = __shfl_xor(k, off);
            k = (o < k) ? o : k;
        }
        if (lane == it) keep = (int)(unsigned)(k & 0xffffffffULL);
        if (key == k) {  // this lane supplied the winner: pop head
#pragma unroll
            for (int s = 0; s < 15; ++s) { bd[s] = bd[s + 1]; bi[s] = bi[s + 1]; }
            bd[15] = 3.4e38f; bi[15] = 0x7fffffff;
        }
    }
    if (lane < 16) idx_out[n * K_NN + lane] = keep;
}

// ---------------------------------------------------------------- proj: T = feats@theta_w+b (fp32), P/G (bf16)
__global__ __launch_bounds__(256) void proj_kernel(
    const bf16_t* __restrict__ fb, const bf16_t* __restrict__ wt_base,
    const float* __restrict__ tb, const float* __restrict__ pb, const float* __restrict__ gb,
    float* __restrict__ T, bf16_t* __restrict__ Pb, bf16_t* __restrict__ Gb) {
    const int sel = blockIdx.y;
    const bf16_t* Wt = wt_base + sel * (C_DIM * C_DIM);
    const float* bias = (sel == 0) ? tb : (sel == 1) ? pb : gb;
    const int wave = threadIdx.x >> 6, lane = threadIdx.x & 63;
    const int q = lane >> 4, lm = lane & 15;
    const int m0 = blockIdx.x * 64 + wave * 16;
    const bf16_t* arow = fb + (m0 + lm) * C_DIM + q * 8;

    f32x4 acc[16];
#pragma unroll
    for (int t = 0; t < 16; ++t) acc[t] = (f32x4){0.f, 0.f, 0.f, 0.f};

#pragma unroll
    for (int kb = 0; kb < 8; ++kb) {
        bf16x8 a = *(const bf16x8*)(arow + kb * 32);
#pragma unroll
        for (int t = 0; t < 16; ++t) {
            bf16x8 b = *(const bf16x8*)(Wt + (t * 16 + lm) * C_DIM + kb * 32 + q * 8);
            acc[t] = __builtin_amdgcn_mfma_f32_16x16x32_bf16(a, b, acc[t], 0, 0, 0);
        }
    }

#pragma unroll
    for (int t = 0; t < 16; ++t) {
        int c = t * 16 + lm;
        float bv = bias[c];
#pragma unroll
        for (int r = 0; r < 4; ++r) {
            float v = acc[t][r] + bv;
            int off = (m0 + q * 4 + r) * C_DIM + c;
            if (sel == 0) T[off] = v;
            else if (sel == 1) Pb[off] = (bf16_t)v;
            else Gb[off] = (bf16_t)v;
        }
    }
}

// ---------------------------------------------------------------- pe1 + pe2 GEMM + softmax + weighted G-sum (fused)
#define HPAD 264  // 256 + 8 bf16 pad (16B) to break 512B-stride LDS conflicts
__global__ __launch_bounds__(256) void pe2_fused_kernel(
    const float* __restrict__ coords, const int* __restrict__ idx,
    const float* __restrict__ T, const bf16_t* __restrict__ Pb, const bf16_t* __restrict__ Gb,
    const float* __restrict__ w1, const float* __restrict__ b1, const float* __restrict__ b2,
    const bf16_t* __restrict__ Wt2, bf16_t* __restrict__ yb) {
    __shared__ __align__(16) bf16_t h_lds[64 * HPAD];
    __shared__ float dxyz[64][3];
    __shared__ int idxl[64];
    const int tid = threadIdx.x;
    const int p0 = blockIdx.x * 4;

    if (tid < 64) {
        int r = tid;
        int n = p0 + (r >> 4);
        int j = idx[n * K_NN + (r & 15)];
        idxl[r] = j;
        dxyz[r][0] = coords[3 * j + 0] - coords[3 * n + 0];
        dxyz[r][1] = coords[3 * j + 1] - coords[3 * n + 1];
        dxyz[r][2] = coords[3 * j + 2] - coords[3 * n + 2];
    }
    __syncthreads();

    {   // pe1: h = relu(delta @ w1 + b1), [64 rows x 256 cols] -> LDS bf16
        int c = tid;
        float wx = w1[c], wy = w1[C_DIM + c], wz = w1[2 * C_DIM + c], bb = b1[c];
#pragma unroll 4
        for (int r = 0; r < 64; ++r) {
            float pre = dxyz[r][0] * wx + dxyz[r][1] * wy + dxyz[r][2] * wz + bb;
            h_lds[r * HPAD + c] = (bf16_t)fmaxf(pre, 0.0f);
        }
    }
    __syncthreads();

    const int wave = tid >> 6, lane = tid & 63;
    const int q = lane >> 4, lm = lane & 15;
    const int n = p0 + wave;
    const bf16_t* hrow = h_lds + (wave * 16 + lm) * HPAD + q * 8;

    f32x4 acc[16];
#pragma unroll
    for (int t = 0; t < 16; ++t) acc[t] = (f32x4){0.f, 0.f, 0.f, 0.f};

#pragma unroll
    for (int kb = 0; kb < 8; ++kb) {
        bf16x8 a = *(const bf16x8*)(hrow + kb * 32);
#pragma unroll
        for (int t = 0; t < 16; ++t) {
            bf16x8 b = *(const bf16x8*)(Wt2 + (t * 16 + lm) * C_DIM + kb * 32 + q * 8);
            acc[t] = __builtin_amdgcn_mfma_f32_16x16x32_bf16(a, b, acc[t], 0, 0, 0);
        }
    }

    // epilogue: this wave owns point n; C-layout row = k = q*4+r, col = t*16+lm
    int jr[4];
#pragma unroll
    for (int r = 0; r < 4; ++r) jr[r] = idxl[wave * 16 + q * 4 + r];

#pragma unroll
    for (int t = 0; t < 16; ++t) {
        int c = t * 16 + lm;
        float Tn = T[n * C_DIM + c];
        float b2c = b2[c];
        float df[4];
#pragma unroll
        for (int r = 0; r < 4; ++r) {
            float pe = acc[t][r] + b2c;
            float phi = (float)Pb[jr[r] * C_DIM + c];
            df[r] = (pe * (Tn - phi) + pe) * 0.0625f;  // /sqrt(256)
        }
        float mx = fmaxf(fmaxf(df[0], df[1]), fmaxf(df[2], df[3]));
        mx = fmaxf(mx, __shfl_xor(mx, 16));
        mx = fmaxf(mx, __shfl_xor(mx, 32));
        float e[4], s = 0.f;
#pragma unroll
        for (int r = 0; r < 4; ++r) { e[r] = __expf(df[r] - mx); s += e[r]; }
        s += __shfl_xor(s, 16);
        s += __shfl_xor(s, 32);
        float inv = 1.0f / s;
        float y = 0.f;
#pragma unroll
        for (int r = 0; r < 4; ++r) y += e[r] * inv * (float)Gb[jr[r] * C_DIM + c];
        y += __shfl_xor(y, 16);
        y += __shfl_xor(y, 32);
        if (q == 0) yb[n * C_DIM + c] = (bf16_t)y;
    }
}

// ---------------------------------------------------------------- final: out = y@W_w + W_b + feats
__global__ __launch_bounds__(256) void final_kernel(
    const bf16_t* __restrict__ yb, const bf16_t* __restrict__ Wt,
    const float* __restrict__ Wb, const float* __restrict__ feats,
    float* __restrict__ out) {
    const int wave = threadIdx.x >> 6, lane = threadIdx.x & 63;
    const int q = lane >> 4, lm = lane & 15;
    const int m0 = blockIdx.x * 64 + wave * 16;
    const bf16_t* arow = yb + (m0 + lm) * C_DIM + q * 8;

    f32x4 acc[16];
#pragma unroll
    for (int t = 0; t < 16; ++t) acc[t] = (f32x4){0.f, 0.f, 0.f, 0.f};

#pragma unroll
    for (int kb = 0; kb < 8; ++kb) {
        bf16x8 a = *(const bf16x8*)(arow + kb * 32);
#pragma unroll
        for (int t = 0; t < 16; ++t) {
            bf16x8 b = *(const bf16x8*)(Wt + (t * 16 + lm) * C_DIM + kb * 32 + q * 8);
            acc[t] = __builtin_amdgcn_mfma_f32_16x16x32_bf16(a, b, acc[t], 0, 0, 0);
        }
    }

#pragma unroll
    for (int t = 0; t < 16; ++t) {
        int c = t * 16 + lm;
        float bv = Wb[c];
#pragma unroll
        for (int r = 0; r < 4; ++r) {
            int off = (m0 + q * 4 + r) * C_DIM + c;
            out[off] = acc[t][r] + bv + feats[off];
        }
    }
}

// ---------------------------------------------------------------- launch
extern "C" void kernel_launch(void* const* d_in, const int* in_sizes, int n_in,
                              void* d_out, int out_size, void* d_ws, size_t ws_size,
                              hipStream_t stream) {
    const float* coords = (const float*)d_in[0];
    const float* feats  = (const float*)d_in[1];
    const float* theta_w = (const float*)d_in[2];
    const float* theta_b = (const float*)d_in[3];
    const float* phi_w   = (const float*)d_in[4];
    const float* phi_b   = (const float*)d_in[5];
    const float* g_w     = (const float*)d_in[6];
    const float* g_b     = (const float*)d_in[7];
    const float* pe1_w1  = (const float*)d_in[8];
    const float* pe1_b1  = (const float*)d_in[9];
    const float* pe1_w2  = (const float*)d_in[10];
    const float* pe1_b2  = (const float*)d_in[11];
    const float* W_w     = (const float*)d_in[12];
    const float* W_b     = (const float*)d_in[13];
    float* out = (float*)d_out;

    char* w = (char*)d_ws;
    size_t off = 0;
    int* idx = (int*)(w + off);        off += (size_t)N_PTS * K_NN * 4;       // 512 KB
    bf16_t* fb = (bf16_t*)(w + off);   off += (size_t)N_PTS * C_DIM * 2;      // 4 MB
    bf16_t* wt = (bf16_t*)(w + off);   off += (size_t)5 * C_DIM * C_DIM * 2;  // 640 KB
    float* T = (float*)(w + off);      off += (size_t)N_PTS * C_DIM * 4;      // 8 MB
    bf16_t* Pb = (bf16_t*)(w + off);   off += (size_t)N_PTS * C_DIM * 2;      // 4 MB
    bf16_t* Gb = (bf16_t*)(w + off);   off += (size_t)N_PTS * C_DIM * 2;      // 4 MB
    bf16_t* yb = (bf16_t*)(w + off);   off += (size_t)N_PTS * C_DIM * 2;      // 4 MB
    (void)ws_size; (void)in_sizes; (void)n_in; (void)out_size;

    cast_feats_kernel<<<(N_PTS * C_DIM) / 1024, 256, 0, stream>>>(feats, fb);
    prep_weights_kernel<<<dim3(4, 4, 5), 256, 0, stream>>>(theta_w, phi_w, g_w, pe1_w2, W_w, wt);
    knn_kernel<<<N_PTS, 64, 0, stream>>>(coords, idx);
    proj_kernel<<<dim3(N_PTS / 64, 3), 256, 0, stream>>>(fb, wt, theta_b, phi_b, g_b, T, Pb, Gb);
    pe2_fused_kernel<<<N_PTS / 4, 256, 0, stream>>>(coords, idx, T, Pb, Gb,
                                                    pe1_w1, pe1_b1, pe1_b2,
                                                    wt + 3 * C_DIM * C_DIM, yb);
    final_kernel<<<N_PTS / 64, 256, 0, stream>>>(yb, wt + 4 * C_DIM * C_DIM, W_b, feats, out);
}

// Round 4
// 518.107 us; speedup vs baseline: 1.8713x; 1.8713x over previous
//
#include <hip/hip_runtime.h>

typedef __bf16 bf16_t;
typedef bf16_t bf16x8 __attribute__((ext_vector_type(8)));
typedef bf16_t bf16x4 __attribute__((ext_vector_type(4)));
typedef float f32x4 __attribute__((ext_vector_type(4)));

#define N_PTS 8192
#define C_DIM 256
#define K_NN 16

// ---------------------------------------------------------------- prep: cast feats to bf16
__global__ __launch_bounds__(256) void cast_feats_kernel(const float* __restrict__ f,
                                                         bf16_t* __restrict__ fb) {
    int i = (blockIdx.x * 256 + threadIdx.x) * 4;
    float4 v = *(const float4*)(f + i);
    bf16x4 o;
    o[0] = (bf16_t)v.x; o[1] = (bf16_t)v.y; o[2] = (bf16_t)v.z; o[3] = (bf16_t)v.w;
    *(bf16x4*)(fb + i) = o;
}

// ---------------------------------------------------------------- prep: transpose+cast 5 weight mats to Wt[n][k] bf16
__global__ __launch_bounds__(256) void prep_weights_kernel(
    const float* __restrict__ w0, const float* __restrict__ w1,
    const float* __restrict__ w2, const float* __restrict__ w3,
    const float* __restrict__ w4, bf16_t* __restrict__ wt_base) {
    __shared__ float tile[64][65];
    int m = blockIdx.z;
    const float* src = (m == 0) ? w0 : (m == 1) ? w1 : (m == 2) ? w2 : (m == 3) ? w3 : w4;
    bf16_t* dst = wt_base + m * (C_DIM * C_DIM);
    int k0 = blockIdx.x * 64, n0 = blockIdx.y * 64;
    int tr = threadIdx.x >> 6, tc = threadIdx.x & 63;
#pragma unroll
    for (int i = 0; i < 16; ++i) {
        int r = i * 4 + tr;
        tile[r][tc] = src[(k0 + r) * C_DIM + (n0 + tc)];
    }
    __syncthreads();
#pragma unroll
    for (int i = 0; i < 16; ++i) {
        int r = i * 4 + tr;
        dst[(n0 + r) * C_DIM + (k0 + tc)] = (bf16_t)tile[tc][r];
    }
}

// ---------------------------------------------------------------- KNN: one 256-thread block per query
// d2 emulates the numpy reference's fp32 rounding EXACTLY (validated round 3):
//   sq   = (fl(x^2)+fl(y^2))+fl(z^2)          (no fma, left-to-right)
//   dot  = fma(z,z', fma(y,y', fl(x*x')))     (BLAS sequential-k fma chain)
//   d2   = fl(fl(sq_i+sq_j) - fl(2*dot))
// Selection: each thread holds 32 distances in REGISTERS (candidates j = s*256+tid),
// caches its local argmin; 16 rounds of block-argmin on packed (ordered_d2, idx) u64.
// Only the winning thread rescans (1/256 divergence). Ties -> lower index (stable top_k).
__global__ __launch_bounds__(256) void knn_kernel(const float* __restrict__ coords,
                                                  int* __restrict__ idx_out) {
    const int n = blockIdx.x;
    const int tid = threadIdx.x;
    __shared__ unsigned long long red[8];  // 4 waves x 2 (round-parity double buffer)

    const float qx = coords[3 * n + 0], qy = coords[3 * n + 1], qz = coords[3 * n + 2];
    const float sqi = __fadd_rn(__fadd_rn(__fmul_rn(qx, qx), __fmul_rn(qy, qy)),
                                __fmul_rn(qz, qz));

    float d[32];
#pragma unroll
    for (int s = 0; s < 32; ++s) {
        int j = s * 256 + tid;
        float xj = coords[3 * j + 0], yj = coords[3 * j + 1], zj = coords[3 * j + 2];
        float sqj = __fadd_rn(__fadd_rn(__fmul_rn(xj, xj), __fmul_rn(yj, yj)),
                              __fmul_rn(zj, zj));
        float dot = __fmaf_rn(zj, qz, __fmaf_rn(yj, qy, __fmul_rn(xj, qx)));
        d[s] = __fsub_rn(__fadd_rn(sqi, sqj), __fmul_rn(2.0f, dot));
    }

    // local argmin over the 32 register slots (strict < -> lowest s -> lowest idx)
    const float INF = __int_as_float(0x7f800000);
    float lbest = d[0];
    int ls = 0;
#pragma unroll
    for (int s = 1; s < 32; ++s)
        if (d[s] < lbest) { lbest = d[s]; ls = s; }

    const int wave = tid >> 6, lane = tid & 63;
    int keep = 0;
#pragma unroll 1
    for (int r = 0; r < 16; ++r) {
        unsigned u = __float_as_uint(lbest);
        u = (u & 0x80000000u) ? ~u : (u | 0x80000000u);
        unsigned long long key =
            (((unsigned long long)u) << 32) | (unsigned)(ls * 256 + tid);
        unsigned long long k = key;
#pragma unroll
        for (int off = 1; off < 64; off <<= 1) {
            unsigned long long o = __shfl_xor(k, off);
            k = (o < k) ? o : k;
        }
        if (lane == 0) red[(r & 1) * 4 + wave] = k;
        __syncthreads();
        unsigned long long k0 = red[(r & 1) * 4 + 0], k1 = red[(r & 1) * 4 + 1];
        unsigned long long k2 = red[(r & 1) * 4 + 2], k3 = red[(r & 1) * 4 + 3];
        k0 = (k1 < k0) ? k1 : k0;
        k2 = (k3 < k2) ? k3 : k2;
        k0 = (k2 < k0) ? k2 : k0;
        int widx = (int)(unsigned)(k0 & 0xffffffffu);
        if (tid == r) keep = widx;
        if ((widx & 255) == tid) {  // winner is mine: mask slot, rescan (no dyn reg index)
            int sw = widx >> 8;
            lbest = INF; ls = 0;
#pragma unroll
            for (int s = 0; s < 32; ++s) {
                if (s == sw) d[s] = INF;
                if (d[s] < lbest) { lbest = d[s]; ls = s; }
            }
        }
    }
    if (tid < 16) idx_out[n * K_NN + tid] = keep;
}

// ---------------------------------------------------------------- proj: T = feats@theta_w+b (fp32), P/G (bf16)
__global__ __launch_bounds__(256) void proj_kernel(
    const bf16_t* __restrict__ fb, const bf16_t* __restrict__ wt_base,
    const float* __restrict__ tb, const float* __restrict__ pb, const float* __restrict__ gb,
    float* __restrict__ T, bf16_t* __restrict__ Pb, bf16_t* __restrict__ Gb) {
    const int sel = blockIdx.y;
    const bf16_t* Wt = wt_base + sel * (C_DIM * C_DIM);
    const float* bias = (sel == 0) ? tb : (sel == 1) ? pb : gb;
    const int wave = threadIdx.x >> 6, lane = threadIdx.x & 63;
    const int q = lane >> 4, lm = lane & 15;
    const int m0 = blockIdx.x * 64 + wave * 16;
    const bf16_t* arow = fb + (m0 + lm) * C_DIM + q * 8;

    f32x4 acc[16];
#pragma unroll
    for (int t = 0; t < 16; ++t) acc[t] = (f32x4){0.f, 0.f, 0.f, 0.f};

#pragma unroll
    for (int kb = 0; kb < 8; ++kb) {
        bf16x8 a = *(const bf16x8*)(arow + kb * 32);
#pragma unroll
        for (int t = 0; t < 16; ++t) {
            bf16x8 b = *(const bf16x8*)(Wt + (t * 16 + lm) * C_DIM + kb * 32 + q * 8);
            acc[t] = __builtin_amdgcn_mfma_f32_16x16x32_bf16(a, b, acc[t], 0, 0, 0);
        }
    }

#pragma unroll
    for (int t = 0; t < 16; ++t) {
        int c = t * 16 + lm;
        float bv = bias[c];
#pragma unroll
        for (int r = 0; r < 4; ++r) {
            float v = acc[t][r] + bv;
            int off = (m0 + q * 4 + r) * C_DIM + c;
            if (sel == 0) T[off] = v;
            else if (sel == 1) Pb[off] = (bf16_t)v;
            else Gb[off] = (bf16_t)v;
        }
    }
}

// ---------------------------------------------------------------- pe1 + pe2 GEMM + softmax + weighted G-sum (fused)
#define HPAD 264  // 256 + 8 bf16 pad (16B) to break 512B-stride LDS conflicts
__global__ __launch_bounds__(256) void pe2_fused_kernel(
    const float* __restrict__ coords, const int* __restrict__ idx,
    const float* __restrict__ T, const bf16_t* __restrict__ Pb, const bf16_t* __restrict__ Gb,
    const float* __restrict__ w1, const float* __restrict__ b1, const float* __restrict__ b2,
    const bf16_t* __restrict__ Wt2, bf16_t* __restrict__ yb) {
    __shared__ __align__(16) bf16_t h_lds[64 * HPAD];
    __shared__ float dxyz[64][3];
    __shared__ int idxl[64];
    const int tid = threadIdx.x;
    const int p0 = blockIdx.x * 4;

    if (tid < 64) {
        int r = tid;
        int n = p0 + (r >> 4);
        int j = idx[n * K_NN + (r & 15)];
        idxl[r] = j;
        dxyz[r][0] = coords[3 * j + 0] - coords[3 * n + 0];
        dxyz[r][1] = coords[3 * j + 1] - coords[3 * n + 1];
        dxyz[r][2] = coords[3 * j + 2] - coords[3 * n + 2];
    }
    __syncthreads();

    {   // pe1: h = relu(delta @ w1 + b1), [64 rows x 256 cols] -> LDS bf16
        int c = tid;
        float wx = w1[c], wy = w1[C_DIM + c], wz = w1[2 * C_DIM + c], bb = b1[c];
#pragma unroll 4
        for (int r = 0; r < 64; ++r) {
            float pre = dxyz[r][0] * wx + dxyz[r][1] * wy + dxyz[r][2] * wz + bb;
            h_lds[r * HPAD + c] = (bf16_t)fmaxf(pre, 0.0f);
        }
    }
    __syncthreads();

    const int wave = tid >> 6, lane = tid & 63;
    const int q = lane >> 4, lm = lane & 15;
    const int n = p0 + wave;
    const bf16_t* hrow = h_lds + (wave * 16 + lm) * HPAD + q * 8;

    f32x4 acc[16];
#pragma unroll
    for (int t = 0; t < 16; ++t) acc[t] = (f32x4){0.f, 0.f, 0.f, 0.f};

#pragma unroll
    for (int kb = 0; kb < 8; ++kb) {
        bf16x8 a = *(const bf16x8*)(hrow + kb * 32);
#pragma unroll
        for (int t = 0; t < 16; ++t) {
            bf16x8 b = *(const bf16x8*)(Wt2 + (t * 16 + lm) * C_DIM + kb * 32 + q * 8);
            acc[t] = __builtin_amdgcn_mfma_f32_16x16x32_bf16(a, b, acc[t], 0, 0, 0);
        }
    }

    // epilogue: this wave owns point n; C-layout row = k = q*4+r, col = t*16+lm
    int jr[4];
#pragma unroll
    for (int r = 0; r < 4; ++r) jr[r] = idxl[wave * 16 + q * 4 + r];

#pragma unroll
    for (int t = 0; t < 16; ++t) {
        int c = t * 16 + lm;
        float Tn = T[n * C_DIM + c];
        float b2c = b2[c];
        float df[4];
#pragma unroll
        for (int r = 0; r < 4; ++r) {
            float pe = acc[t][r] + b2c;
            float phi = (float)Pb[jr[r] * C_DIM + c];
            df[r] = (pe * (Tn - phi) + pe) * 0.0625f;  // /sqrt(256)
        }
        float mx = fmaxf(fmaxf(df[0], df[1]), fmaxf(df[2], df[3]));
        mx = fmaxf(mx, __shfl_xor(mx, 16));
        mx = fmaxf(mx, __shfl_xor(mx, 32));
        float e[4], s = 0.f;
#pragma unroll
        for (int r = 0; r < 4; ++r) { e[r] = __expf(df[r] - mx); s += e[r]; }
        s += __shfl_xor(s, 16);
        s += __shfl_xor(s, 32);
        float inv = 1.0f / s;
        float y = 0.f;
#pragma unroll
        for (int r = 0; r < 4; ++r) y += e[r] * inv * (float)Gb[jr[r] * C_DIM + c];
        y += __shfl_xor(y, 16);
        y += __shfl_xor(y, 32);
        if (q == 0) yb[n * C_DIM + c] = (bf16_t)y;
    }
}

// ---------------------------------------------------------------- final: out = y@W_w + W_b + feats
__global__ __launch_bounds__(256) void final_kernel(
    const bf16_t* __restrict__ yb, const bf16_t* __restrict__ Wt,
    const float* __restrict__ Wb, const float* __restrict__ feats,
    float* __restrict__ out) {
    const int wave = threadIdx.x >> 6, lane = threadIdx.x & 63;
    const int q = lane >> 4, lm = lane & 15;
    const int m0 = blockIdx.x * 64 + wave * 16;
    const bf16_t* arow = yb + (m0 + lm) * C_DIM + q * 8;

    f32x4 acc[16];
#pragma unroll
    for (int t = 0; t < 16; ++t) acc[t] = (f32x4){0.f, 0.f, 0.f, 0.f};

#pragma unroll
    for (int kb = 0; kb < 8; ++kb) {
        bf16x8 a = *(const bf16x8*)(arow + kb * 32);
#pragma unroll
        for (int t = 0; t < 16; ++t) {
            bf16x8 b = *(const bf16x8*)(Wt + (t * 16 + lm) * C_DIM + kb * 32 + q * 8);
            acc[t] = __builtin_amdgcn_mfma_f32_16x16x32_bf16(a, b, acc[t], 0, 0, 0);
        }
    }

#pragma unroll
    for (int t = 0; t < 16; ++t) {
        int c = t * 16 + lm;
        float bv = Wb[c];
#pragma unroll
        for (int r = 0; r < 4; ++r) {
            int off = (m0 + q * 4 + r) * C_DIM + c;
            out[off] = acc[t][r] + bv + feats[off];
        }
    }
}

// ---------------------------------------------------------------- launch
extern "C" void kernel_launch(void* const* d_in, const int* in_sizes, int n_in,
                              void* d_out, int out_size, void* d_ws, size_t ws_size,
                              hipStream_t stream) {
    const float* coords = (const float*)d_in[0];
    const float* feats  = (const float*)d_in[1];
    const float* theta_w = (const float*)d_in[2];
    const float* theta_b = (const float*)d_in[3];
    const float* phi_w   = (const float*)d_in[4];
    const float* phi_b   = (const float*)d_in[5];
    const float* g_w     = (const float*)d_in[6];
    const float* g_b     = (const float*)d_in[7];
    const float* pe1_w1  = (const float*)d_in[8];
    const float* pe1_b1  = (const float*)d_in[9];
    const float* pe1_w2  = (const float*)d_in[10];
    const float* pe1_b2  = (const float*)d_in[11];
    const float* W_w     = (const float*)d_in[12];
    const float* W_b     = (const float*)d_in[13];
    float* out = (float*)d_out;

    char* w = (char*)d_ws;
    size_t off = 0;
    int* idx = (int*)(w + off);        off += (size_t)N_PTS * K_NN * 4;       // 512 KB
    bf16_t* fb = (bf16_t*)(w + off);   off += (size_t)N_PTS * C_DIM * 2;      // 4 MB
    bf16_t* wt = (bf16_t*)(w + off);   off += (size_t)5 * C_DIM * C_DIM * 2;  // 640 KB
    float* T = (float*)(w + off);      off += (size_t)N_PTS * C_DIM * 4;      // 8 MB
    bf16_t* Pb = (bf16_t*)(w + off);   off += (size_t)N_PTS * C_DIM * 2;      // 4 MB
    bf16_t* Gb = (bf16_t*)(w + off);   off += (size_t)N_PTS * C_DIM * 2;      // 4 MB
    bf16_t* yb = (bf16_t*)(w + off);   off += (size_t)N_PTS * C_DIM * 2;      // 4 MB
    (void)ws_size; (void)in_sizes; (void)n_in; (void)out_size;

    cast_feats_kernel<<<(N_PTS * C_DIM) / 1024, 256, 0, stream>>>(feats, fb);
    prep_weights_kernel<<<dim3(4, 4, 5), 256, 0, stream>>>(theta_w, phi_w, g_w, pe1_w2, W_w, wt);
    knn_kernel<<<N_PTS, 256, 0, stream>>>(coords, idx);
    proj_kernel<<<dim3(N_PTS / 64, 3), 256, 0, stream>>>(fb, wt, theta_b, phi_b, g_b, T, Pb, Gb);
    pe2_fused_kernel<<<N_PTS / 4, 256, 0, stream>>>(coords, idx, T, Pb, Gb,
                                                    pe1_w1, pe1_b1, pe1_b2,
                                                    wt + 3 * C_DIM * C_DIM, yb);
    final_kernel<<<N_PTS / 64, 256, 0, stream>>>(yb, wt + 4 * C_DIM * C_DIM, W_b, feats, out);
}

// Round 5
// 416.735 us; speedup vs baseline: 2.3265x; 1.2433x over previous
//
#include <hip/hip_runtime.h>

typedef __bf16 bf16_t;
typedef bf16_t bf16x8 __attribute__((ext_vector_type(8)));
typedef bf16_t bf16x4 __attribute__((ext_vector_type(4)));
typedef float f32x4 __attribute__((ext_vector_type(4)));

#define N_PTS 8192
#define C_DIM 256
#define K_NN 16

// ---------------------------------------------------------------- prep: cast feats to bf16
__global__ __launch_bounds__(256) void cast_feats_kernel(const float* __restrict__ f,
                                                         bf16_t* __restrict__ fb) {
    int i = (blockIdx.x * 256 + threadIdx.x) * 4;
    float4 v = *(const float4*)(f + i);
    bf16x4 o;
    o[0] = (bf16_t)v.x; o[1] = (bf16_t)v.y; o[2] = (bf16_t)v.z; o[3] = (bf16_t)v.w;
    *(bf16x4*)(fb + i) = o;
}

// ---------------------------------------------------------------- prep: weights -> MFMA B-fragment-major bf16
// Layout: Wt[((t*8+kb)*512) + lm*32 + q*8 + e] = W[k = kb*32+q*8+e][n = t*16+lm].
// A wave's B-load for (t,kb) then reads a CONTIGUOUS 1 KB (vs 512B-stride = 64 cache
// lines per instruction in the old row-major-transposed layout).
__global__ __launch_bounds__(256) void prep_weights_kernel(
    const float* __restrict__ w0, const float* __restrict__ w1,
    const float* __restrict__ w2, const float* __restrict__ w3,
    const float* __restrict__ w4, bf16_t* __restrict__ wt_base) {
    int m = blockIdx.y;
    const float* src = (m == 0) ? w0 : (m == 1) ? w1 : (m == 2) ? w2 : (m == 3) ? w3 : w4;
    bf16_t* dst = wt_base + m * (C_DIM * C_DIM);
#pragma unroll
    for (int i = 0; i < 4; ++i) {
        int o = blockIdx.x * 1024 + i * 256 + threadIdx.x;
        int tkb = o >> 9;           // t*8 + kb
        int rem = o & 511;
        int lm = rem >> 5;
        int r = rem & 31;           // q*8 + e
        int k = (tkb & 7) * 32 + r;
        int n = (tkb >> 3) * 16 + lm;
        dst[o] = (bf16_t)src[k * C_DIM + n];
    }
}

// ---------------------------------------------------------------- KNN: one 256-thread block per query
// d2 emulates the numpy reference's fp32 rounding EXACTLY (validated round 3):
//   sq  = (fl(x^2)+fl(y^2))+fl(z^2); dot = fma(z,z',fma(y,y',fl(x*x')));
//   d2  = fl(fl(sq_i+sq_j) - fl(2*dot))
// Selection: threshold prefilter. tau = max of 16 disjoint group-mins (each a real
// candidate => >=16 candidates have d2 <= tau; expected survivors ~44 of 8192).
// Survivors compact to LDS via one atomic counter; wave 0 extracts top-16 by unique
// (ordered_d2, idx) u64 keys — no block-wide barrier rounds. Exact same neighbor set
// and order as rounds 3/4 (ties -> lower index).
__global__ __launch_bounds__(256) void knn_kernel(const float* __restrict__ coords,
                                                  int* __restrict__ idx_out) {
    const int n = blockIdx.x;
    const int tid = threadIdx.x;
    const int wave = tid >> 6, lane = tid & 63;
    __shared__ float red16[16];
    __shared__ unsigned long long cand[256];
    __shared__ unsigned long long sel16[16];
    __shared__ int cnt;

    if (tid == 0) cnt = 0;

    const float qx = coords[3 * n + 0], qy = coords[3 * n + 1], qz = coords[3 * n + 2];
    const float sqi = __fadd_rn(__fadd_rn(__fmul_rn(qx, qx), __fmul_rn(qy, qy)),
                                __fmul_rn(qz, qz));

    // thread t owns points j = t*32 + s (contiguous 96 floats -> 24 float4 loads)
    float d[32];
    const float* cp = coords + tid * 96;
#pragma unroll
    for (int c = 0; c < 4; ++c) {
        float buf[24];
#pragma unroll
        for (int v = 0; v < 6; ++v)
            *(float4*)(buf + v * 4) = *(const float4*)(cp + c * 24 + v * 4);
#pragma unroll
        for (int p = 0; p < 8; ++p) {
            float x = buf[3 * p + 0], y = buf[3 * p + 1], z = buf[3 * p + 2];
            float sqj = __fadd_rn(__fadd_rn(__fmul_rn(x, x), __fmul_rn(y, y)),
                                  __fmul_rn(z, z));
            float dot = __fmaf_rn(z, qz, __fmaf_rn(y, qy, __fmul_rn(x, qx)));
            d[c * 8 + p] = __fsub_rn(__fadd_rn(sqi, sqj), __fmul_rn(2.0f, dot));
        }
    }

    // per-thread min, then 16-lane group mins -> tau bound
    float lmin = d[0];
#pragma unroll
    for (int s = 1; s < 32; ++s) lmin = fminf(lmin, d[s]);
    float g = lmin;
    g = fminf(g, __shfl_xor(g, 1));
    g = fminf(g, __shfl_xor(g, 2));
    g = fminf(g, __shfl_xor(g, 4));
    g = fminf(g, __shfl_xor(g, 8));
    if ((lane & 15) == 0) red16[wave * 4 + (lane >> 4)] = g;
    __syncthreads();

    float tau = red16[0];
#pragma unroll
    for (int i = 1; i < 16; ++i) tau = fmaxf(tau, red16[i]);

    // compact survivors (mostly execz-skipped)
#pragma unroll
    for (int s = 0; s < 32; ++s) {
        if (d[s] <= tau) {
            unsigned u = __float_as_uint(d[s]);
            u = (u & 0x80000000u) ? ~u : (u | 0x80000000u);
            int slot = atomicAdd(&cnt, 1);
            if (slot < 256)
                cand[slot] = (((unsigned long long)u) << 32) | (unsigned)(tid * 32 + s);
        }
    }
    __syncthreads();

    // wave 0: top-16 of <=256 candidates, 16 wave-argmin rounds (keys unique)
    if (wave == 0) {
        int m = cnt; if (m > 256) m = 256;
        unsigned long long k0 = ~0ull, k1 = ~0ull, k2 = ~0ull, k3 = ~0ull;
        if (lane < m) k0 = cand[lane];
        if (lane + 64 < m) k1 = cand[lane + 64];
        if (lane + 128 < m) k2 = cand[lane + 128];
        if (lane + 192 < m) k3 = cand[lane + 192];
        unsigned long long lm2 = k0; int li = 0;
        if (k1 < lm2) { lm2 = k1; li = 1; }
        if (k2 < lm2) { lm2 = k2; li = 2; }
        if (k3 < lm2) { lm2 = k3; li = 3; }
#pragma unroll 1
        for (int r = 0; r < 16; ++r) {
            unsigned long long w = lm2;
#pragma unroll
            for (int off = 1; off < 64; off <<= 1) {
                unsigned long long o = __shfl_xor(w, off);
                w = (o < w) ? o : w;
            }
            if (lane == 0) sel16[r] = w;
            if (lm2 == w) {  // unique winner: retire slot, recompute local min
                if (li == 0) k0 = ~0ull;
                else if (li == 1) k1 = ~0ull;
                else if (li == 2) k2 = ~0ull;
                else k3 = ~0ull;
                lm2 = k0; li = 0;
                if (k1 < lm2) { lm2 = k1; li = 1; }
                if (k2 < lm2) { lm2 = k2; li = 2; }
                if (k3 < lm2) { lm2 = k3; li = 3; }
            }
        }
    }
    __syncthreads();
    if (tid < 16) idx_out[n * K_NN + tid] = (int)(unsigned)(sel16[tid] & 0xffffffffull);
}

// ---------------------------------------------------------------- proj: T = feats@theta_w+b (fp32), P/G (bf16)
__global__ __launch_bounds__(256) void proj_kernel(
    const bf16_t* __restrict__ fb, const bf16_t* __restrict__ wt_base,
    const float* __restrict__ tb, const float* __restrict__ pb, const float* __restrict__ gb,
    float* __restrict__ T, bf16_t* __restrict__ Pb, bf16_t* __restrict__ Gb) {
    const int sel = blockIdx.y;
    const bf16_t* Wt = wt_base + sel * (C_DIM * C_DIM);
    const float* bias = (sel == 0) ? tb : (sel == 1) ? pb : gb;
    const int wave = threadIdx.x >> 6, lane = threadIdx.x & 63;
    const int q = lane >> 4, lm = lane & 15;
    const int m0 = blockIdx.x * 64 + wave * 16;
    const bf16_t* arow = fb + (m0 + lm) * C_DIM + q * 8;

    f32x4 acc[16];
#pragma unroll
    for (int t = 0; t < 16; ++t) acc[t] = (f32x4){0.f, 0.f, 0.f, 0.f};

#pragma unroll
    for (int kb = 0; kb < 8; ++kb) {
        bf16x8 a = *(const bf16x8*)(arow + kb * 32);
#pragma unroll
        for (int t = 0; t < 16; ++t) {
            bf16x8 b = *(const bf16x8*)(Wt + ((t * 8 + kb) << 9) + lm * 32 + q * 8);
            acc[t] = __builtin_amdgcn_mfma_f32_16x16x32_bf16(a, b, acc[t], 0, 0, 0);
        }
    }

#pragma unroll
    for (int t = 0; t < 16; ++t) {
        int c = t * 16 + lm;
        float bv = bias[c];
#pragma unroll
        for (int r = 0; r < 4; ++r) {
            float v = acc[t][r] + bv;
            int off = (m0 + q * 4 + r) * C_DIM + c;
            if (sel == 0) T[off] = v;
            else if (sel == 1) Pb[off] = (bf16_t)v;
            else Gb[off] = (bf16_t)v;
        }
    }
}

// ---------------------------------------------------------------- pe1 + pe2 GEMM + softmax + weighted G-sum (fused)
#define HPAD 264  // 256 + 8 bf16 pad (16B) to break 512B-stride LDS conflicts
__global__ __launch_bounds__(256) void pe2_fused_kernel(
    const float* __restrict__ coords, const int* __restrict__ idx,
    const float* __restrict__ T, const bf16_t* __restrict__ Pb, const bf16_t* __restrict__ Gb,
    const float* __restrict__ w1, const float* __restrict__ b1, const float* __restrict__ b2,
    const bf16_t* __restrict__ Wt2, bf16_t* __restrict__ yb) {
    __shared__ __align__(16) bf16_t h_lds[64 * HPAD];
    __shared__ float dxyz[64][3];
    __shared__ int idxl[64];
    const int tid = threadIdx.x;
    const int p0 = blockIdx.x * 4;

    if (tid < 64) {
        int r = tid;
        int n = p0 + (r >> 4);
        int j = idx[n * K_NN + (r & 15)];
        idxl[r] = j;
        dxyz[r][0] = coords[3 * j + 0] - coords[3 * n + 0];
        dxyz[r][1] = coords[3 * j + 1] - coords[3 * n + 1];
        dxyz[r][2] = coords[3 * j + 2] - coords[3 * n + 2];
    }
    __syncthreads();

    {   // pe1: h = relu(delta @ w1 + b1), [64 rows x 256 cols] -> LDS bf16
        int c = tid;
        float wx = w1[c], wy = w1[C_DIM + c], wz = w1[2 * C_DIM + c], bb = b1[c];
#pragma unroll 4
        for (int r = 0; r < 64; ++r) {
            float pre = dxyz[r][0] * wx + dxyz[r][1] * wy + dxyz[r][2] * wz + bb;
            h_lds[r * HPAD + c] = (bf16_t)fmaxf(pre, 0.0f);
        }
    }
    __syncthreads();

    const int wave = tid >> 6, lane = tid & 63;
    const int q = lane >> 4, lm = lane & 15;
    const int n = p0 + wave;
    const bf16_t* hrow = h_lds + (wave * 16 + lm) * HPAD + q * 8;

    f32x4 acc[16];
#pragma unroll
    for (int t = 0; t < 16; ++t) acc[t] = (f32x4){0.f, 0.f, 0.f, 0.f};

#pragma unroll
    for (int kb = 0; kb < 8; ++kb) {
        bf16x8 a = *(const bf16x8*)(hrow + kb * 32);
#pragma unroll
        for (int t = 0; t < 16; ++t) {
            bf16x8 b = *(const bf16x8*)(Wt2 + ((t * 8 + kb) << 9) + lm * 32 + q * 8);
            acc[t] = __builtin_amdgcn_mfma_f32_16x16x32_bf16(a, b, acc[t], 0, 0, 0);
        }
    }

    // epilogue: this wave owns point n; C-layout row = k = q*4+r, col = t*16+lm
    int jr[4];
#pragma unroll
    for (int r = 0; r < 4; ++r) jr[r] = idxl[wave * 16 + q * 4 + r];

#pragma unroll
    for (int t = 0; t < 16; ++t) {
        int c = t * 16 + lm;
        float Tn = T[n * C_DIM + c];
        float b2c = b2[c];
        float df[4];
#pragma unroll
        for (int r = 0; r < 4; ++r) {
            float pe = acc[t][r] + b2c;
            float phi = (float)Pb[jr[r] * C_DIM + c];
            df[r] = (pe * (Tn - phi) + pe) * 0.0625f;  // /sqrt(256)
        }
        float mx = fmaxf(fmaxf(df[0], df[1]), fmaxf(df[2], df[3]));
        mx = fmaxf(mx, __shfl_xor(mx, 16));
        mx = fmaxf(mx, __shfl_xor(mx, 32));
        float e[4], s = 0.f;
#pragma unroll
        for (int r = 0; r < 4; ++r) { e[r] = __expf(df[r] - mx); s += e[r]; }
        s += __shfl_xor(s, 16);
        s += __shfl_xor(s, 32);
        float inv = 1.0f / s;
        float y = 0.f;
#pragma unroll
        for (int r = 0; r < 4; ++r) y += e[r] * inv * (float)Gb[jr[r] * C_DIM + c];
        y += __shfl_xor(y, 16);
        y += __shfl_xor(y, 32);
        if (q == 0) yb[n * C_DIM + c] = (bf16_t)y;
    }
}

// ---------------------------------------------------------------- final: out = y@W_w + W_b + feats
__global__ __launch_bounds__(256) void final_kernel(
    const bf16_t* __restrict__ yb, const bf16_t* __restrict__ Wt,
    const float* __restrict__ Wb, const float* __restrict__ feats,
    float* __restrict__ out) {
    const int wave = threadIdx.x >> 6, lane = threadIdx.x & 63;
    const int q = lane >> 4, lm = lane & 15;
    const int m0 = blockIdx.x * 64 + wave * 16;
    const bf16_t* arow = yb + (m0 + lm) * C_DIM + q * 8;

    f32x4 acc[16];
#pragma unroll
    for (int t = 0; t < 16; ++t) acc[t] = (f32x4){0.f, 0.f, 0.f, 0.f};

#pragma unroll
    for (int kb = 0; kb < 8; ++kb) {
        bf16x8 a = *(const bf16x8*)(arow + kb * 32);
#pragma unroll
        for (int t = 0; t < 16; ++t) {
            bf16x8 b = *(const bf16x8*)(Wt + ((t * 8 + kb) << 9) + lm * 32 + q * 8);
            acc[t] = __builtin_amdgcn_mfma_f32_16x16x32_bf16(a, b, acc[t], 0, 0, 0);
        }
    }

#pragma unroll
    for (int t = 0; t < 16; ++t) {
        int c = t * 16 + lm;
        float bv = Wb[c];
#pragma unroll
        for (int r = 0; r < 4; ++r) {
            int off = (m0 + q * 4 + r) * C_DIM + c;
            out[off] = acc[t][r] + bv + feats[off];
        }
    }
}

// ---------------------------------------------------------------- launch
extern "C" void kernel_launch(void* const* d_in, const int* in_sizes, int n_in,
                              void* d_out, int out_size, void* d_ws, size_t ws_size,
                              hipStream_t stream) {
    const float* coords = (const float*)d_in[0];
    const float* feats  = (const float*)d_in[1];
    const float* theta_w = (const float*)d_in[2];
    const float* theta_b = (const float*)d_in[3];
    const float* phi_w   = (const float*)d_in[4];
    const float* phi_b   = (const float*)d_in[5];
    const float* g_w     = (const float*)d_in[6];
    const float* g_b     = (const float*)d_in[7];
    const float* pe1_w1  = (const float*)d_in[8];
    const float* pe1_b1  = (const float*)d_in[9];
    const float* pe1_w2  = (const float*)d_in[10];
    const float* pe1_b2  = (const float*)d_in[11];
    const float* W_w     = (const float*)d_in[12];
    const float* W_b     = (const float*)d_in[13];
    float* out = (float*)d_out;

    char* w = (char*)d_ws;
    size_t off = 0;
    int* idx = (int*)(w + off);        off += (size_t)N_PTS * K_NN * 4;       // 512 KB
    bf16_t* fb = (bf16_t*)(w + off);   off += (size_t)N_PTS * C_DIM * 2;      // 4 MB
    bf16_t* wt = (bf16_t*)(w + off);   off += (size_t)5 * C_DIM * C_DIM * 2;  // 640 KB
    float* T = (float*)(w + off);      off += (size_t)N_PTS * C_DIM * 4;      // 8 MB
    bf16_t* Pb = (bf16_t*)(w + off);   off += (size_t)N_PTS * C_DIM * 2;      // 4 MB
    bf16_t* Gb = (bf16_t*)(w + off);   off += (size_t)N_PTS * C_DIM * 2;      // 4 MB
    bf16_t* yb = (bf16_t*)(w + off);   off += (size_t)N_PTS * C_DIM * 2;      // 4 MB
    (void)ws_size; (void)in_sizes; (void)n_in; (void)out_size;

    cast_feats_kernel<<<(N_PTS * C_DIM) / 1024, 256, 0, stream>>>(feats, fb);
    prep_weights_kernel<<<dim3(64, 5), 256, 0, stream>>>(theta_w, phi_w, g_w, pe1_w2, W_w, wt);
    knn_kernel<<<N_PTS, 256, 0, stream>>>(coords, idx);
    proj_kernel<<<dim3(N_PTS / 64, 3), 256, 0, stream>>>(fb, wt, theta_b, phi_b, g_b, T, Pb, Gb);
    pe2_fused_kernel<<<N_PTS / 4, 256, 0, stream>>>(coords, idx, T, Pb, Gb,
                                                    pe1_w1, pe1_b1, pe1_b2,
                                                    wt + 3 * C_DIM * C_DIM, yb);
    final_kernel<<<N_PTS / 64, 256, 0, stream>>>(yb, wt + 4 * C_DIM * C_DIM, W_b, feats, out);
}

// Round 6
// 288.045 us; speedup vs baseline: 3.3660x; 1.4468x over previous
//
#include <hip/hip_runtime.h>

typedef __bf16 bf16_t;
typedef bf16_t bf16x8 __attribute__((ext_vector_type(8)));
typedef bf16_t bf16x4 __attribute__((ext_vector_type(4)));
typedef float f32x4 __attribute__((ext_vector_type(4)));

#define N_PTS 8192
#define C_DIM 256
#define K_NN 16

// ---------------------------------------------------------------- prep: cast feats to bf16
__global__ __launch_bounds__(256) void cast_feats_kernel(const float* __restrict__ f,
                                                         bf16_t* __restrict__ fb) {
    int i = (blockIdx.x * 256 + threadIdx.x) * 4;
    float4 v = *(const float4*)(f + i);
    bf16x4 o;
    o[0] = (bf16_t)v.x; o[1] = (bf16_t)v.y; o[2] = (bf16_t)v.z; o[3] = (bf16_t)v.w;
    *(bf16x4*)(fb + i) = o;
}

// ---------------------------------------------------------------- prep: weights -> MFMA B-fragment-major bf16
// Wt[((t*8+kb)*512) + lm*32 + q*8 + e] = W[k = kb*32+q*8+e][n = t*16+lm].
__global__ __launch_bounds__(256) void prep_weights_kernel(
    const float* __restrict__ w0, const float* __restrict__ w1,
    const float* __restrict__ w2, const float* __restrict__ w3,
    const float* __restrict__ w4, bf16_t* __restrict__ wt_base) {
    int m = blockIdx.y;
    const float* src = (m == 0) ? w0 : (m == 1) ? w1 : (m == 2) ? w2 : (m == 3) ? w3 : w4;
    bf16_t* dst = wt_base + m * (C_DIM * C_DIM);
#pragma unroll
    for (int i = 0; i < 4; ++i) {
        int o = blockIdx.x * 1024 + i * 256 + threadIdx.x;
        int tkb = o >> 9;           // t*8 + kb
        int rem = o & 511;
        int lm = rem >> 5;
        int r = rem & 31;           // q*8 + e
        int k = (tkb & 7) * 32 + r;
        int n = (tkb >> 3) * 16 + lm;
        dst[o] = (bf16_t)src[k * C_DIM + n];
    }
}

// ---------------------------------------------------------------- KNN (validated: exact ref d2 bits; threshold prefilter)
__global__ __launch_bounds__(256) void knn_kernel(const float* __restrict__ coords,
                                                  int* __restrict__ idx_out) {
    const int n = blockIdx.x;
    const int tid = threadIdx.x;
    const int wave = tid >> 6, lane = tid & 63;
    __shared__ float red16[16];
    __shared__ unsigned long long cand[256];
    __shared__ unsigned long long sel16[16];
    __shared__ int cnt;

    if (tid == 0) cnt = 0;

    const float qx = coords[3 * n + 0], qy = coords[3 * n + 1], qz = coords[3 * n + 2];
    const float sqi = __fadd_rn(__fadd_rn(__fmul_rn(qx, qx), __fmul_rn(qy, qy)),
                                __fmul_rn(qz, qz));

    float d[32];
    const float* cp = coords + tid * 96;
#pragma unroll
    for (int c = 0; c < 4; ++c) {
        float buf[24];
#pragma unroll
        for (int v = 0; v < 6; ++v)
            *(float4*)(buf + v * 4) = *(const float4*)(cp + c * 24 + v * 4);
#pragma unroll
        for (int p = 0; p < 8; ++p) {
            float x = buf[3 * p + 0], y = buf[3 * p + 1], z = buf[3 * p + 2];
            float sqj = __fadd_rn(__fadd_rn(__fmul_rn(x, x), __fmul_rn(y, y)),
                                  __fmul_rn(z, z));
            float dot = __fmaf_rn(z, qz, __fmaf_rn(y, qy, __fmul_rn(x, qx)));
            d[c * 8 + p] = __fsub_rn(__fadd_rn(sqi, sqj), __fmul_rn(2.0f, dot));
        }
    }

    float lmin = d[0];
#pragma unroll
    for (int s = 1; s < 32; ++s) lmin = fminf(lmin, d[s]);
    float g = lmin;
    g = fminf(g, __shfl_xor(g, 1));
    g = fminf(g, __shfl_xor(g, 2));
    g = fminf(g, __shfl_xor(g, 4));
    g = fminf(g, __shfl_xor(g, 8));
    if ((lane & 15) == 0) red16[wave * 4 + (lane >> 4)] = g;
    __syncthreads();

    float tau = red16[0];
#pragma unroll
    for (int i = 1; i < 16; ++i) tau = fmaxf(tau, red16[i]);

#pragma unroll
    for (int s = 0; s < 32; ++s) {
        if (d[s] <= tau) {
            unsigned u = __float_as_uint(d[s]);
            u = (u & 0x80000000u) ? ~u : (u | 0x80000000u);
            int slot = atomicAdd(&cnt, 1);
            if (slot < 256)
                cand[slot] = (((unsigned long long)u) << 32) | (unsigned)(tid * 32 + s);
        }
    }
    __syncthreads();

    if (wave == 0) {
        int m = cnt; if (m > 256) m = 256;
        unsigned long long k0 = ~0ull, k1 = ~0ull, k2 = ~0ull, k3 = ~0ull;
        if (lane < m) k0 = cand[lane];
        if (lane + 64 < m) k1 = cand[lane + 64];
        if (lane + 128 < m) k2 = cand[lane + 128];
        if (lane + 192 < m) k3 = cand[lane + 192];
        unsigned long long lm2 = k0; int li = 0;
        if (k1 < lm2) { lm2 = k1; li = 1; }
        if (k2 < lm2) { lm2 = k2; li = 2; }
        if (k3 < lm2) { lm2 = k3; li = 3; }
#pragma unroll 1
        for (int r = 0; r < 16; ++r) {
            unsigned long long w = lm2;
#pragma unroll
            for (int off = 1; off < 64; off <<= 1) {
                unsigned long long o = __shfl_xor(w, off);
                w = (o < w) ? o : w;
            }
            if (lane == 0) sel16[r] = w;
            if (lm2 == w) {
                if (li == 0) k0 = ~0ull;
                else if (li == 1) k1 = ~0ull;
                else if (li == 2) k2 = ~0ull;
                else k3 = ~0ull;
                lm2 = k0; li = 0;
                if (k1 < lm2) { lm2 = k1; li = 1; }
                if (k2 < lm2) { lm2 = k2; li = 2; }
                if (k3 < lm2) { lm2 = k3; li = 3; }
            }
        }
    }
    __syncthreads();
    if (tid < 16) idx_out[n * K_NN + tid] = (int)(unsigned)(sel16[tid] & 0xffffffffull);
}

// ---------------------------------------------------------------- proj: T/P/G = feats@{theta,phi,g}+b
// B-reuse split: wave owns t = wave*4+ti (4 col-tiles, B preloaded in regs),
// loops p over 4 row-tiles -> per-wave B traffic 32 KB (was 128 KB).
__global__ __launch_bounds__(256, 2) void proj_kernel(
    const bf16_t* __restrict__ fb, const bf16_t* __restrict__ wt_base,
    const float* __restrict__ tb, const float* __restrict__ pb, const float* __restrict__ gb,
    float* __restrict__ T, bf16_t* __restrict__ Pb, bf16_t* __restrict__ Gb) {
    const int sel = blockIdx.y;
    const bf16_t* Wt = wt_base + sel * (C_DIM * C_DIM);
    const float* bias = (sel == 0) ? tb : (sel == 1) ? pb : gb;
    const int wave = threadIdx.x >> 6, lane = threadIdx.x & 63;
    const int q = lane >> 4, lm = lane & 15;
    const int m0 = blockIdx.x * 64;

    bf16x8 bfr[4][8];
#pragma unroll
    for (int ti = 0; ti < 4; ++ti)
#pragma unroll
        for (int kb = 0; kb < 8; ++kb)
            bfr[ti][kb] = *(const bf16x8*)(Wt + (((wave * 4 + ti) * 8 + kb) << 9) + lm * 32 + q * 8);

    float bv[4];
#pragma unroll
    for (int ti = 0; ti < 4; ++ti) bv[ti] = bias[(wave * 4 + ti) * 16 + lm];

#pragma unroll
    for (int p = 0; p < 4; ++p) {
        const bf16_t* arow = fb + (m0 + p * 16 + lm) * C_DIM + q * 8;
        bf16x8 a[8];
#pragma unroll
        for (int kb = 0; kb < 8; ++kb) a[kb] = *(const bf16x8*)(arow + kb * 32);
        f32x4 acc[4];
#pragma unroll
        for (int ti = 0; ti < 4; ++ti) acc[ti] = (f32x4){0.f, 0.f, 0.f, 0.f};
#pragma unroll
        for (int ti = 0; ti < 4; ++ti)
#pragma unroll
            for (int kb = 0; kb < 8; ++kb)
                acc[ti] = __builtin_amdgcn_mfma_f32_16x16x32_bf16(a[kb], bfr[ti][kb], acc[ti], 0, 0, 0);

#pragma unroll
        for (int ti = 0; ti < 4; ++ti) {
            int c = (wave * 4 + ti) * 16 + lm;
#pragma unroll
            for (int r = 0; r < 4; ++r) {
                float v = acc[ti][r] + bv[ti];
                int off = (m0 + p * 16 + q * 4 + r) * C_DIM + c;
                if (sel == 0) T[off] = v;
                else if (sel == 1) Pb[off] = (bf16_t)v;
                else Gb[off] = (bf16_t)v;
            }
        }
    }
}

// ---------------------------------------------------------------- pe1 + pe2 GEMM + softmax + weighted G-sum (fused)
// Block = 8 points (128 h-rows in LDS). Wave owns 4 col-tiles; B (32 frags) preloaded
// once into registers and reused across all 8 points -> B L2 traffic 1.07GB -> 134MB.
// Epilogue issues Pb AND Gb gathers together (one L2 round-trip, not two).
#define HPAD 264  // 256 + 8 bf16 pad
#define P_BLK 8
#define HROWS (P_BLK * 16)
__global__ __launch_bounds__(256, 2) void pe2_fused_kernel(
    const float* __restrict__ coords, const int* __restrict__ idx,
    const float* __restrict__ T, const bf16_t* __restrict__ Pb, const bf16_t* __restrict__ Gb,
    const float* __restrict__ w1, const float* __restrict__ b1, const float* __restrict__ b2,
    const bf16_t* __restrict__ Wt2, bf16_t* __restrict__ yb) {
    __shared__ __align__(16) bf16_t h_lds[HROWS * HPAD];
    __shared__ float dxyz[HROWS][3];
    __shared__ int idxl[HROWS];
    const int tid = threadIdx.x;
    const int p0 = blockIdx.x * P_BLK;
    const int wave = tid >> 6, lane = tid & 63;
    const int q = lane >> 4, lm = lane & 15;

    // B preload: independent of LDS — issue first, vmcnt-waits at first MFMA use
    bf16x8 bfr[4][8];
#pragma unroll
    for (int ti = 0; ti < 4; ++ti)
#pragma unroll
        for (int kb = 0; kb < 8; ++kb)
            bfr[ti][kb] = *(const bf16x8*)(Wt2 + (((wave * 4 + ti) * 8 + kb) << 9) + lm * 32 + q * 8);
    float b2c[4];
#pragma unroll
    for (int ti = 0; ti < 4; ++ti) b2c[ti] = b2[(wave * 4 + ti) * 16 + lm];

    if (tid < HROWS) {
        int n = p0 + (tid >> 4);
        int j = idx[n * K_NN + (tid & 15)];
        idxl[tid] = j;
        dxyz[tid][0] = coords[3 * j + 0] - coords[3 * n + 0];
        dxyz[tid][1] = coords[3 * j + 1] - coords[3 * n + 1];
        dxyz[tid][2] = coords[3 * j + 2] - coords[3 * n + 2];
    }
    __syncthreads();

    {   // pe1: h = relu(delta @ w1 + b1) -> LDS bf16 (thread owns col c = tid)
        int c = tid;
        float wx = w1[c], wy = w1[C_DIM + c], wz = w1[2 * C_DIM + c], bb = b1[c];
#pragma unroll 4
        for (int r = 0; r < HROWS; ++r) {
            float pre = dxyz[r][0] * wx + dxyz[r][1] * wy + dxyz[r][2] * wz + bb;
            h_lds[r * HPAD + c] = (bf16_t)fmaxf(pre, 0.0f);
        }
    }
    __syncthreads();

#pragma unroll 1
    for (int lp = 0; lp < P_BLK; ++lp) {
        const int n = p0 + lp;
        const bf16_t* hrow = h_lds + (lp * 16 + lm) * HPAD + q * 8;
        bf16x8 a[8];
#pragma unroll
        for (int kb = 0; kb < 8; ++kb) a[kb] = *(const bf16x8*)(hrow + kb * 32);
        f32x4 acc[4];
#pragma unroll
        for (int ti = 0; ti < 4; ++ti) acc[ti] = (f32x4){0.f, 0.f, 0.f, 0.f};
#pragma unroll
        for (int ti = 0; ti < 4; ++ti)
#pragma unroll
            for (int kb = 0; kb < 8; ++kb)
                acc[ti] = __builtin_amdgcn_mfma_f32_16x16x32_bf16(a[kb], bfr[ti][kb], acc[ti], 0, 0, 0);

        int jr[4];
#pragma unroll
        for (int r = 0; r < 4; ++r) jr[r] = idxl[lp * 16 + q * 4 + r];

#pragma unroll
        for (int ti = 0; ti < 4; ++ti) {
            int c = (wave * 4 + ti) * 16 + lm;
            // issue both gathers up front — one L2 round-trip
            float phi[4], gv[4];
#pragma unroll
            for (int r = 0; r < 4; ++r) {
                phi[r] = (float)Pb[jr[r] * C_DIM + c];
                gv[r]  = (float)Gb[jr[r] * C_DIM + c];
            }
            float Tn = T[n * C_DIM + c];
            float df[4];
#pragma unroll
            for (int r = 0; r < 4; ++r) {
                float pe = acc[ti][r] + b2c[ti];
                df[r] = (pe * (Tn - phi[r]) + pe) * 0.0625f;  // /sqrt(256)
            }
            float mx = fmaxf(fmaxf(df[0], df[1]), fmaxf(df[2], df[3]));
            mx = fmaxf(mx, __shfl_xor(mx, 16));
            mx = fmaxf(mx, __shfl_xor(mx, 32));
            float e[4], s = 0.f;
#pragma unroll
            for (int r = 0; r < 4; ++r) { e[r] = __expf(df[r] - mx); s += e[r]; }
            s += __shfl_xor(s, 16);
            s += __shfl_xor(s, 32);
            float inv = 1.0f / s;
            float y = 0.f;
#pragma unroll
            for (int r = 0; r < 4; ++r) y += e[r] * inv * gv[r];
            y += __shfl_xor(y, 16);
            y += __shfl_xor(y, 32);
            if (q == 0) yb[n * C_DIM + c] = (bf16_t)y;
        }
    }
}

// ---------------------------------------------------------------- final: out = y@W_w + W_b + feats
__global__ __launch_bounds__(256, 2) void final_kernel(
    const bf16_t* __restrict__ yb, const bf16_t* __restrict__ Wt,
    const float* __restrict__ Wb, const float* __restrict__ feats,
    float* __restrict__ out) {
    const int wave = threadIdx.x >> 6, lane = threadIdx.x & 63;
    const int q = lane >> 4, lm = lane & 15;
    const int m0 = blockIdx.x * 64;

    bf16x8 bfr[4][8];
#pragma unroll
    for (int ti = 0; ti < 4; ++ti)
#pragma unroll
        for (int kb = 0; kb < 8; ++kb)
            bfr[ti][kb] = *(const bf16x8*)(Wt + (((wave * 4 + ti) * 8 + kb) << 9) + lm * 32 + q * 8);
    float bv[4];
#pragma unroll
    for (int ti = 0; ti < 4; ++ti) bv[ti] = Wb[(wave * 4 + ti) * 16 + lm];

#pragma unroll
    for (int p = 0; p < 4; ++p) {
        const bf16_t* arow = yb + (m0 + p * 16 + lm) * C_DIM + q * 8;
        bf16x8 a[8];
#pragma unroll
        for (int kb = 0; kb < 8; ++kb) a[kb] = *(const bf16x8*)(arow + kb * 32);
        f32x4 acc[4];
#pragma unroll
        for (int ti = 0; ti < 4; ++ti) acc[ti] = (f32x4){0.f, 0.f, 0.f, 0.f};
#pragma unroll
        for (int ti = 0; ti < 4; ++ti)
#pragma unroll
            for (int kb = 0; kb < 8; ++kb)
                acc[ti] = __builtin_amdgcn_mfma_f32_16x16x32_bf16(a[kb], bfr[ti][kb], acc[ti], 0, 0, 0);

#pragma unroll
        for (int ti = 0; ti < 4; ++ti) {
            int c = (wave * 4 + ti) * 16 + lm;
#pragma unroll
            for (int r = 0; r < 4; ++r) {
                int off = (m0 + p * 16 + q * 4 + r) * C_DIM + c;
                out[off] = acc[ti][r] + bv[ti] + feats[off];
            }
        }
    }
}

// ---------------------------------------------------------------- launch
extern "C" void kernel_launch(void* const* d_in, const int* in_sizes, int n_in,
                              void* d_out, int out_size, void* d_ws, size_t ws_size,
                              hipStream_t stream) {
    const float* coords = (const float*)d_in[0];
    const float* feats  = (const float*)d_in[1];
    const float* theta_w = (const float*)d_in[2];
    const float* theta_b = (const float*)d_in[3];
    const float* phi_w   = (const float*)d_in[4];
    const float* phi_b   = (const float*)d_in[5];
    const float* g_w     = (const float*)d_in[6];
    const float* g_b     = (const float*)d_in[7];
    const float* pe1_w1  = (const float*)d_in[8];
    const float* pe1_b1  = (const float*)d_in[9];
    const float* pe1_w2  = (const float*)d_in[10];
    const float* pe1_b2  = (const float*)d_in[11];
    const float* W_w     = (const float*)d_in[12];
    const float* W_b     = (const float*)d_in[13];
    float* out = (float*)d_out;

    char* w = (char*)d_ws;
    size_t off = 0;
    int* idx = (int*)(w + off);        off += (size_t)N_PTS * K_NN * 4;       // 512 KB
    bf16_t* fb = (bf16_t*)(w + off);   off += (size_t)N_PTS * C_DIM * 2;      // 4 MB
    bf16_t* wt = (bf16_t*)(w + off);   off += (size_t)5 * C_DIM * C_DIM * 2;  // 640 KB
    float* T = (float*)(w + off);      off += (size_t)N_PTS * C_DIM * 4;      // 8 MB
    bf16_t* Pb = (bf16_t*)(w + off);   off += (size_t)N_PTS * C_DIM * 2;      // 4 MB
    bf16_t* Gb = (bf16_t*)(w + off);   off += (size_t)N_PTS * C_DIM * 2;      // 4 MB
    bf16_t* yb = (bf16_t*)(w + off);   off += (size_t)N_PTS * C_DIM * 2;      // 4 MB
    (void)ws_size; (void)in_sizes; (void)n_in; (void)out_size;

    cast_feats_kernel<<<(N_PTS * C_DIM) / 1024, 256, 0, stream>>>(feats, fb);
    prep_weights_kernel<<<dim3(64, 5), 256, 0, stream>>>(theta_w, phi_w, g_w, pe1_w2, W_w, wt);
    knn_kernel<<<N_PTS, 256, 0, stream>>>(coords, idx);
    proj_kernel<<<dim3(N_PTS / 64, 3), 256, 0, stream>>>(fb, wt, theta_b, phi_b, g_b, T, Pb, Gb);
    pe2_fused_kernel<<<N_PTS / P_BLK, 256, 0, stream>>>(coords, idx, T, Pb, Gb,
                                                        pe1_w1, pe1_b1, pe1_b2,
                                                        wt + 3 * C_DIM * C_DIM, yb);
    final_kernel<<<N_PTS / 64, 256, 0, stream>>>(yb, wt + 4 * C_DIM * C_DIM, W_b, feats, out);
}

// Round 7
// 262.728 us; speedup vs baseline: 3.6903x; 1.0964x over previous
//
#include <hip/hip_runtime.h>

typedef __bf16 bf16_t;
typedef bf16_t bf16x8 __attribute__((ext_vector_type(8)));
typedef bf16_t bf16x4 __attribute__((ext_vector_type(4)));
typedef float f32x4 __attribute__((ext_vector_type(4)));

#define N_PTS 8192
#define C_DIM 256
#define K_NN 16

// ---------------------------------------------------------------- prep: cast feats to bf16
__global__ __launch_bounds__(256) void cast_feats_kernel(const float* __restrict__ f,
                                                         bf16_t* __restrict__ fb) {
    int i = (blockIdx.x * 256 + threadIdx.x) * 4;
    float4 v = *(const float4*)(f + i);
    bf16x4 o;
    o[0] = (bf16_t)v.x; o[1] = (bf16_t)v.y; o[2] = (bf16_t)v.z; o[3] = (bf16_t)v.w;
    *(bf16x4*)(fb + i) = o;
}

// ---------------------------------------------------------------- prep: weights -> MFMA B-fragment-major bf16
// Wt[((t*8+kb)*512) + lm*32 + q*8 + e] = W[k = kb*32+q*8+e][n = t*16+lm].
__global__ __launch_bounds__(256) void prep_weights_kernel(
    const float* __restrict__ w0, const float* __restrict__ w1,
    const float* __restrict__ w2, const float* __restrict__ w3,
    const float* __restrict__ w4, bf16_t* __restrict__ wt_base) {
    int m = blockIdx.y;
    const float* src = (m == 0) ? w0 : (m == 1) ? w1 : (m == 2) ? w2 : (m == 3) ? w3 : w4;
    bf16_t* dst = wt_base + m * (C_DIM * C_DIM);
#pragma unroll
    for (int i = 0; i < 4; ++i) {
        int o = blockIdx.x * 1024 + i * 256 + threadIdx.x;
        int tkb = o >> 9;           // t*8 + kb
        int rem = o & 511;
        int lm = rem >> 5;
        int r = rem & 31;           // q*8 + e
        int k = (tkb & 7) * 32 + r;
        int n = (tkb >> 3) * 16 + lm;
        dst[o] = (bf16_t)src[k * C_DIM + n];
    }
}

// ---------------------------------------------------------------- KNN: 4 queries per 256-thread block
// d2 bits emulate the numpy reference exactly (validated rounds 3-6):
//   sq  = (fl(x^2)+fl(y^2))+fl(z^2); dot = fma(z,z',fma(y,y',fl(x*x')));
//   d2  = fl(fl(sq_i+sq_j) - fl(2*dot))
// Pass 1: one coord stream serves all 4 queries (per-thread mins -> 16 disjoint
// group-mins -> tau[q]; provably tau >= 16th-NN dist). Pass 2: reload from hot L1,
// recompute identical d2 bits, compact survivors per query (~44 expected of 8192).
// Selection: wave w extracts top-16 for query w by unique (ordered_d2, idx) u64 keys —
// all 4 waves busy, no cross-wave rounds. Ties -> lower index (stable top_k).
__global__ __launch_bounds__(256) void knn_kernel(const float* __restrict__ coords,
                                                  int* __restrict__ idx_out) {
    const int tid = threadIdx.x;
    const int wave = tid >> 6, lane = tid & 63;
    const int n0 = blockIdx.x * 4;
    __shared__ float red16[4][16];
    __shared__ unsigned long long cand[4][256];
    __shared__ int cnt[4];

    if (tid < 4) cnt[tid] = 0;

    float qx[4], qy[4], qz[4], sqi[4];
#pragma unroll
    for (int q = 0; q < 4; ++q) {
        qx[q] = coords[3 * (n0 + q) + 0];
        qy[q] = coords[3 * (n0 + q) + 1];
        qz[q] = coords[3 * (n0 + q) + 2];
        sqi[q] = __fadd_rn(__fadd_rn(__fmul_rn(qx[q], qx[q]), __fmul_rn(qy[q], qy[q])),
                           __fmul_rn(qz[q], qz[q]));
    }

    const float INF = __int_as_float(0x7f800000);
    const float* cp = coords + tid * 96;

    // ---- pass 1: per-thread min per query over owned 32 points
    float lmin[4] = {INF, INF, INF, INF};
#pragma unroll
    for (int c = 0; c < 4; ++c) {
        float buf[24];
#pragma unroll
        for (int v = 0; v < 6; ++v)
            *(float4*)(buf + v * 4) = *(const float4*)(cp + c * 24 + v * 4);
#pragma unroll
        for (int p = 0; p < 8; ++p) {
            float x = buf[3 * p + 0], y = buf[3 * p + 1], z = buf[3 * p + 2];
            float sqj = __fadd_rn(__fadd_rn(__fmul_rn(x, x), __fmul_rn(y, y)),
                                  __fmul_rn(z, z));
#pragma unroll
            for (int q = 0; q < 4; ++q) {
                float dot = __fmaf_rn(z, qz[q], __fmaf_rn(y, qy[q], __fmul_rn(x, qx[q])));
                float d2 = __fsub_rn(__fadd_rn(sqi[q], sqj), __fmul_rn(2.0f, dot));
                lmin[q] = fminf(lmin[q], d2);
            }
        }
    }

    // ---- 16 disjoint group-mins (groups of 16 threads = 512 points) -> tau per query
#pragma unroll
    for (int q = 0; q < 4; ++q) {
        float g = lmin[q];
        g = fminf(g, __shfl_xor(g, 1));
        g = fminf(g, __shfl_xor(g, 2));
        g = fminf(g, __shfl_xor(g, 4));
        g = fminf(g, __shfl_xor(g, 8));
        if ((lane & 15) == 0) red16[q][wave * 4 + (lane >> 4)] = g;
    }
    __syncthreads();

    float tau[4];
#pragma unroll
    for (int q = 0; q < 4; ++q) {
        float t = red16[q][0];
#pragma unroll
        for (int i = 1; i < 16; ++i) t = fmaxf(t, red16[q][i]);
        tau[q] = t;
    }

    // ---- pass 2: reload (L1-hot), recompute identical d2 bits, compact survivors
#pragma unroll
    for (int c = 0; c < 4; ++c) {
        float buf[24];
#pragma unroll
        for (int v = 0; v < 6; ++v)
            *(float4*)(buf + v * 4) = *(const float4*)(cp + c * 24 + v * 4);
#pragma unroll
        for (int p = 0; p < 8; ++p) {
            float x = buf[3 * p + 0], y = buf[3 * p + 1], z = buf[3 * p + 2];
            float sqj = __fadd_rn(__fadd_rn(__fmul_rn(x, x), __fmul_rn(y, y)),
                                  __fmul_rn(z, z));
            int j = tid * 32 + c * 8 + p;
#pragma unroll
            for (int q = 0; q < 4; ++q) {
                float dot = __fmaf_rn(z, qz[q], __fmaf_rn(y, qy[q], __fmul_rn(x, qx[q])));
                float d2 = __fsub_rn(__fadd_rn(sqi[q], sqj), __fmul_rn(2.0f, dot));
                if (d2 <= tau[q]) {
                    unsigned u = __float_as_uint(d2);
                    u = (u & 0x80000000u) ? ~u : (u | 0x80000000u);
                    int slot = atomicAdd(&cnt[q], 1);
                    if (slot < 256)
                        cand[q][slot] = (((unsigned long long)u) << 32) | (unsigned)j;
                }
            }
        }
    }
    __syncthreads();

    // ---- selection: wave w -> query w, 16 wave-argmin rounds over <=256 unique keys
    int m = cnt[wave]; if (m > 256) m = 256;
    unsigned long long k0 = ~0ull, k1 = ~0ull, k2 = ~0ull, k3 = ~0ull;
    if (lane < m) k0 = cand[wave][lane];
    if (lane + 64 < m) k1 = cand[wave][lane + 64];
    if (lane + 128 < m) k2 = cand[wave][lane + 128];
    if (lane + 192 < m) k3 = cand[wave][lane + 192];
    unsigned long long lm2 = k0; int li = 0;
    if (k1 < lm2) { lm2 = k1; li = 1; }
    if (k2 < lm2) { lm2 = k2; li = 2; }
    if (k3 < lm2) { lm2 = k3; li = 3; }
    int keep = 0;
#pragma unroll 1
    for (int r = 0; r < 16; ++r) {
        unsigned long long w = lm2;
#pragma unroll
        for (int off = 1; off < 64; off <<= 1) {
            unsigned long long o = __shfl_xor(w, off);
            w = (o < w) ? o : w;
        }
        if (lane == r) keep = (int)(unsigned)(w & 0xffffffffull);
        if (lm2 == w) {  // unique winner: retire slot, recompute local min
            if (li == 0) k0 = ~0ull;
            else if (li == 1) k1 = ~0ull;
            else if (li == 2) k2 = ~0ull;
            else k3 = ~0ull;
            lm2 = k0; li = 0;
            if (k1 < lm2) { lm2 = k1; li = 1; }
            if (k2 < lm2) { lm2 = k2; li = 2; }
            if (k3 < lm2) { lm2 = k3; li = 3; }
        }
    }
    if (lane < 16) idx_out[(n0 + wave) * K_NN + lane] = keep;
}

// ---------------------------------------------------------------- proj: T/P/G = feats@{theta,phi,g}+b
// B-reuse split: wave owns 4 col-tiles (B preloaded in regs), loops 4 row-tiles.
__global__ __launch_bounds__(256, 2) void proj_kernel(
    const bf16_t* __restrict__ fb, const bf16_t* __restrict__ wt_base,
    const float* __restrict__ tb, const float* __restrict__ pb, const float* __restrict__ gb,
    float* __restrict__ T, bf16_t* __restrict__ Pb, bf16_t* __restrict__ Gb) {
    const int sel = blockIdx.y;
    const bf16_t* Wt = wt_base + sel * (C_DIM * C_DIM);
    const float* bias = (sel == 0) ? tb : (sel == 1) ? pb : gb;
    const int wave = threadIdx.x >> 6, lane = threadIdx.x & 63;
    const int q = lane >> 4, lm = lane & 15;
    const int m0 = blockIdx.x * 64;

    bf16x8 bfr[4][8];
#pragma unroll
    for (int ti = 0; ti < 4; ++ti)
#pragma unroll
        for (int kb = 0; kb < 8; ++kb)
            bfr[ti][kb] = *(const bf16x8*)(Wt + (((wave * 4 + ti) * 8 + kb) << 9) + lm * 32 + q * 8);

    float bv[4];
#pragma unroll
    for (int ti = 0; ti < 4; ++ti) bv[ti] = bias[(wave * 4 + ti) * 16 + lm];

#pragma unroll
    for (int p = 0; p < 4; ++p) {
        const bf16_t* arow = fb + (m0 + p * 16 + lm) * C_DIM + q * 8;
        bf16x8 a[8];
#pragma unroll
        for (int kb = 0; kb < 8; ++kb) a[kb] = *(const bf16x8*)(arow + kb * 32);
        f32x4 acc[4];
#pragma unroll
        for (int ti = 0; ti < 4; ++ti) acc[ti] = (f32x4){0.f, 0.f, 0.f, 0.f};
#pragma unroll
        for (int ti = 0; ti < 4; ++ti)
#pragma unroll
            for (int kb = 0; kb < 8; ++kb)
                acc[ti] = __builtin_amdgcn_mfma_f32_16x16x32_bf16(a[kb], bfr[ti][kb], acc[ti], 0, 0, 0);

#pragma unroll
        for (int ti = 0; ti < 4; ++ti) {
            int c = (wave * 4 + ti) * 16 + lm;
#pragma unroll
            for (int r = 0; r < 4; ++r) {
                float v = acc[ti][r] + bv[ti];
                int off = (m0 + p * 16 + q * 4 + r) * C_DIM + c;
                if (sel == 0) T[off] = v;
                else if (sel == 1) Pb[off] = (bf16_t)v;
                else Gb[off] = (bf16_t)v;
            }
        }
    }
}

// ---------------------------------------------------------------- pe1 + pe2 GEMM + softmax + weighted G-sum (fused)
#define HPAD 264  // 256 + 8 bf16 pad
#define P_BLK 8
#define HROWS (P_BLK * 16)
__global__ __launch_bounds__(256, 2) void pe2_fused_kernel(
    const float* __restrict__ coords, const int* __restrict__ idx,
    const float* __restrict__ T, const bf16_t* __restrict__ Pb, const bf16_t* __restrict__ Gb,
    const float* __restrict__ w1, const float* __restrict__ b1, const float* __restrict__ b2,
    const bf16_t* __restrict__ Wt2, bf16_t* __restrict__ yb) {
    __shared__ __align__(16) bf16_t h_lds[HROWS * HPAD];
    __shared__ float dxyz[HROWS][3];
    __shared__ int idxl[HROWS];
    const int tid = threadIdx.x;
    const int p0 = blockIdx.x * P_BLK;
    const int wave = tid >> 6, lane = tid & 63;
    const int q = lane >> 4, lm = lane & 15;

    bf16x8 bfr[4][8];
#pragma unroll
    for (int ti = 0; ti < 4; ++ti)
#pragma unroll
        for (int kb = 0; kb < 8; ++kb)
            bfr[ti][kb] = *(const bf16x8*)(Wt2 + (((wave * 4 + ti) * 8 + kb) << 9) + lm * 32 + q * 8);
    float b2c[4];
#pragma unroll
    for (int ti = 0; ti < 4; ++ti) b2c[ti] = b2[(wave * 4 + ti) * 16 + lm];

    if (tid < HROWS) {
        int n = p0 + (tid >> 4);
        int j = idx[n * K_NN + (tid & 15)];
        idxl[tid] = j;
        dxyz[tid][0] = coords[3 * j + 0] - coords[3 * n + 0];
        dxyz[tid][1] = coords[3 * j + 1] - coords[3 * n + 1];
        dxyz[tid][2] = coords[3 * j + 2] - coords[3 * n + 2];
    }
    __syncthreads();

    {   // pe1: h = relu(delta @ w1 + b1) -> LDS bf16 (thread owns col c = tid)
        int c = tid;
        float wx = w1[c], wy = w1[C_DIM + c], wz = w1[2 * C_DIM + c], bb = b1[c];
#pragma unroll 4
        for (int r = 0; r < HROWS; ++r) {
            float pre = dxyz[r][0] * wx + dxyz[r][1] * wy + dxyz[r][2] * wz + bb;
            h_lds[r * HPAD + c] = (bf16_t)fmaxf(pre, 0.0f);
        }
    }
    __syncthreads();

#pragma unroll 1
    for (int lp = 0; lp < P_BLK; ++lp) {
        const int n = p0 + lp;
        const bf16_t* hrow = h_lds + (lp * 16 + lm) * HPAD + q * 8;
        bf16x8 a[8];
#pragma unroll
        for (int kb = 0; kb < 8; ++kb) a[kb] = *(const bf16x8*)(hrow + kb * 32);
        f32x4 acc[4];
#pragma unroll
        for (int ti = 0; ti < 4; ++ti) acc[ti] = (f32x4){0.f, 0.f, 0.f, 0.f};
#pragma unroll
        for (int ti = 0; ti < 4; ++ti)
#pragma unroll
            for (int kb = 0; kb < 8; ++kb)
                acc[ti] = __builtin_amdgcn_mfma_f32_16x16x32_bf16(a[kb], bfr[ti][kb], acc[ti], 0, 0, 0);

        int jr[4];
#pragma unroll
        for (int r = 0; r < 4; ++r) jr[r] = idxl[lp * 16 + q * 4 + r];

#pragma unroll
        for (int ti = 0; ti < 4; ++ti) {
            int c = (wave * 4 + ti) * 16 + lm;
            float phi[4], gv[4];
#pragma unroll
            for (int r = 0; r < 4; ++r) {
                phi[r] = (float)Pb[jr[r] * C_DIM + c];
                gv[r]  = (float)Gb[jr[r] * C_DIM + c];
            }
            float Tn = T[n * C_DIM + c];
            float df[4];
#pragma unroll
            for (int r = 0; r < 4; ++r) {
                float pe = acc[ti][r] + b2c[ti];
                df[r] = (pe * (Tn - phi[r]) + pe) * 0.0625f;  // /sqrt(256)
            }
            float mx = fmaxf(fmaxf(df[0], df[1]), fmaxf(df[2], df[3]));
            mx = fmaxf(mx, __shfl_xor(mx, 16));
            mx = fmaxf(mx, __shfl_xor(mx, 32));
            float e[4], s = 0.f;
#pragma unroll
            for (int r = 0; r < 4; ++r) { e[r] = __expf(df[r] - mx); s += e[r]; }
            s += __shfl_xor(s, 16);
            s += __shfl_xor(s, 32);
            float inv = 1.0f / s;
            float y = 0.f;
#pragma unroll
            for (int r = 0; r < 4; ++r) y += e[r] * inv * gv[r];
            y += __shfl_xor(y, 16);
            y += __shfl_xor(y, 32);
            if (q == 0) yb[n * C_DIM + c] = (bf16_t)y;
        }
    }
}

// ---------------------------------------------------------------- final: out = y@W_w + W_b + feats
__global__ __launch_bounds__(256, 2) void final_kernel(
    const bf16_t* __restrict__ yb, const bf16_t* __restrict__ Wt,
    const float* __restrict__ Wb, const float* __restrict__ feats,
    float* __restrict__ out) {
    const int wave = threadIdx.x >> 6, lane = threadIdx.x & 63;
    const int q = lane >> 4, lm = lane & 15;
    const int m0 = blockIdx.x * 64;

    bf16x8 bfr[4][8];
#pragma unroll
    for (int ti = 0; ti < 4; ++ti)
#pragma unroll
        for (int kb = 0; kb < 8; ++kb)
            bfr[ti][kb] = *(const bf16x8*)(Wt + (((wave * 4 + ti) * 8 + kb) << 9) + lm * 32 + q * 8);
    float bv[4];
#pragma unroll
    for (int ti = 0; ti < 4; ++ti) bv[ti] = Wb[(wave * 4 + ti) * 16 + lm];

#pragma unroll
    for (int p = 0; p < 4; ++p) {
        const bf16_t* arow = yb + (m0 + p * 16 + lm) * C_DIM + q * 8;
        bf16x8 a[8];
#pragma unroll
        for (int kb = 0; kb < 8; ++kb) a[kb] = *(const bf16x8*)(arow + kb * 32);
        f32x4 acc[4];
#pragma unroll
        for (int ti = 0; ti < 4; ++ti) acc[ti] = (f32x4){0.f, 0.f, 0.f, 0.f};
#pragma unroll
        for (int ti = 0; ti < 4; ++ti)
#pragma unroll
            for (int kb = 0; kb < 8; ++kb)
                acc[ti] = __builtin_amdgcn_mfma_f32_16x16x32_bf16(a[kb], bfr[ti][kb], acc[ti], 0, 0, 0);

#pragma unroll
        for (int ti = 0; ti < 4; ++ti) {
            int c = (wave * 4 + ti) * 16 + lm;
#pragma unroll
            for (int r = 0; r < 4; ++r) {
                int off = (m0 + p * 16 + q * 4 + r) * C_DIM + c;
                out[off] = acc[ti][r] + bv[ti] + feats[off];
            }
        }
    }
}

// ---------------------------------------------------------------- launch
extern "C" void kernel_launch(void* const* d_in, const int* in_sizes, int n_in,
                              void* d_out, int out_size, void* d_ws, size_t ws_size,
                              hipStream_t stream) {
    const float* coords = (const float*)d_in[0];
    const float* feats  = (const float*)d_in[1];
    const float* theta_w = (const float*)d_in[2];
    const float* theta_b = (const float*)d_in[3];
    const float* phi_w   = (const float*)d_in[4];
    const float* phi_b   = (const float*)d_in[5];
    const float* g_w     = (const float*)d_in[6];
    const float* g_b     = (const float*)d_in[7];
    const float* pe1_w1  = (const float*)d_in[8];
    const float* pe1_b1  = (const float*)d_in[9];
    const float* pe1_w2  = (const float*)d_in[10];
    const float* pe1_b2  = (const float*)d_in[11];
    const float* W_w     = (const float*)d_in[12];
    const float* W_b     = (const float*)d_in[13];
    float* out = (float*)d_out;

    char* w = (char*)d_ws;
    size_t off = 0;
    int* idx = (int*)(w + off);        off += (size_t)N_PTS * K_NN * 4;       // 512 KB
    bf16_t* fb = (bf16_t*)(w + off);   off += (size_t)N_PTS * C_DIM * 2;      // 4 MB
    bf16_t* wt = (bf16_t*)(w + off);   off += (size_t)5 * C_DIM * C_DIM * 2;  // 640 KB
    float* T = (float*)(w + off);      off += (size_t)N_PTS * C_DIM * 4;      // 8 MB
    bf16_t* Pb = (bf16_t*)(w + off);   off += (size_t)N_PTS * C_DIM * 2;      // 4 MB
    bf16_t* Gb = (bf16_t*)(w + off);   off += (size_t)N_PTS * C_DIM * 2;      // 4 MB
    bf16_t* yb = (bf16_t*)(w + off);   off += (size_t)N_PTS * C_DIM * 2;      // 4 MB
    (void)ws_size; (void)in_sizes; (void)n_in; (void)out_size;

    cast_feats_kernel<<<(N_PTS * C_DIM) / 1024, 256, 0, stream>>>(feats, fb);
    prep_weights_kernel<<<dim3(64, 5), 256, 0, stream>>>(theta_w, phi_w, g_w, pe1_w2, W_w, wt);
    knn_kernel<<<N_PTS / 4, 256, 0, stream>>>(coords, idx);
    proj_kernel<<<dim3(N_PTS / 64, 3), 256, 0, stream>>>(fb, wt, theta_b, phi_b, g_b, T, Pb, Gb);
    pe2_fused_kernel<<<N_PTS / P_BLK, 256, 0, stream>>>(coords, idx, T, Pb, Gb,
                                                        pe1_w1, pe1_b1, pe1_b2,
                                                        wt + 3 * C_DIM * C_DIM, yb);
    final_kernel<<<N_PTS / 64, 256, 0, stream>>>(yb, wt + 4 * C_DIM * C_DIM, W_b, feats, out);
}